// Round 1
// baseline (648.634 us; speedup 1.0000x reference)
//
#include <hip/hip_runtime.h>
#include <hip/hip_bf16.h>
#include <stdint.h>
#include <stddef.h>

#define B_  8192
#define T_  658
#define I_  7
#define TP  672     // T padded to multiple of 32 (GEMM1 K)
#define D1_ 1024
#define D2_ 512
#define D3_ 128
#define NP4 768     // T padded to multiple of 128 (GEMM4 N)

typedef __bf16 bf16x8 __attribute__((ext_vector_type(8)));
typedef float  floatx4 __attribute__((ext_vector_type(4)));

__device__ __forceinline__ void gload_lds16(const void* g, void* l) {
    __builtin_amdgcn_global_load_lds(
        (const __attribute__((address_space(1))) void*)g,
        (__attribute__((address_space(3))) void*)l, 16, 0, 0);
}

// ---------------- Kernel 1: xw[b,t] = sum_i x[b,t,i]*Wih[i] + bih ------------
// Layout: xw is [B, T] fp32. Grid covers B*T exactly (5390336 = 21056*256).
__global__ void xw_kernel(const float* __restrict__ x,
                          const float* __restrict__ Wih,
                          const float* __restrict__ bih,
                          float* __restrict__ xw) {
    const size_t i = (size_t)blockIdx.x * 256 + threadIdx.x;   // over B*T
    const float* xp = x + i * I_;
    float s = bih[0];
#pragma unroll
    for (int j = 0; j < I_; ++j) s = fmaf(xp[j], Wih[j], s);
    xw[i] = s;
}

// ---------------- Kernel 2: sequential tanh scan, one thread per batch row ---
// Writes A0 (bf16 [B, TP], cols T_..TP-1 zeroed) and h_last (fp32 [B]).
__global__ void scan_kernel(const float* __restrict__ xw,
                            const float* __restrict__ h0,
                            const float* __restrict__ Whh,
                            const float* __restrict__ bhh,
                            __bf16* __restrict__ A0,
                            float* __restrict__ hlast) {
    const int b = blockIdx.x * 256 + threadIdx.x;   // 8192 threads
    float h = h0[b];
    const float whh = Whh[0], bh = bhh[0];
    const float* row = xw + (size_t)b * T_;
    __bf16* orow = A0 + (size_t)b * TP;
#pragma unroll 4
    for (int t = 0; t < T_; ++t) {
        h = tanhf(fmaf(h, whh, row[t] + bh));
        orow[t] = (__bf16)h;
    }
#pragma unroll
    for (int t = T_; t < TP; ++t) orow[t] = (__bf16)0.0f;
    hlast[b] = h;
}

// ---------------- Kernel 3: fp32 -> bf16 weight conversion (with padding) ----
// w1b [D1][TP] (cols >= T_ zero), w2b [D2][D1], w3b [D3][D2], w4b [NP4][D3] (rows >= T_ zero)
__global__ void convert_weights(const float* __restrict__ w1, const float* __restrict__ w2,
                                const float* __restrict__ w3, const float* __restrict__ w4,
                                __bf16* __restrict__ w1b, __bf16* __restrict__ w2b,
                                __bf16* __restrict__ w3b, __bf16* __restrict__ w4b) {
    int i = blockIdx.x * 256 + threadIdx.x;
    if (i < D1_ * TP) {
        int r = i / TP, c = i - r * TP;
        w1b[i] = (__bf16)(c < T_ ? w1[r * T_ + c] : 0.0f);
        return;
    }
    i -= D1_ * TP;
    if (i < D2_ * D1_) { w2b[i] = (__bf16)w2[i]; return; }
    i -= D2_ * D1_;
    if (i < D3_ * D2_) { w3b[i] = (__bf16)w3[i]; return; }
    i -= D3_ * D2_;
    {   // NP4*D3 elements
        int r = i / D3_, c = i - r * D3_;
        w4b[i] = (__bf16)(r < T_ ? w4[r * D3_ + c] : 0.0f);
    }
}

// ---------------- Kernel 4: bf16 MFMA GEMM, C = relu(A @ W^T + bias) ---------
// A: [M=8192, K] bf16 row-major (K multiple of 32)
// W: [Npad, K]  bf16 row-major ("B^T" layout)
// outb (bf16 [M, Npad]) if non-null, else outf (fp32 [M, Nreal]) with n < Nreal.
// 128x128 tile, BK=32, 256 threads (4 waves, 2x2 of 64x64), 16x16x32 MFMA.
__global__ __launch_bounds__(256, 2) void gemm_bt(
    const __bf16* __restrict__ A, const __bf16* __restrict__ W,
    const float* __restrict__ bias, __bf16* __restrict__ outb,
    float* __restrict__ outf, int K, int Npad, int Nreal, int relu) {
    __shared__ __align__(16) __bf16 As[128 * 32];
    __shared__ __align__(16) __bf16 Bs[128 * 32];

    const int tid = threadIdx.x;
    const int m0 = blockIdx.x * 128, n0 = blockIdx.y * 128;
    const int lane = tid & 63, wave = tid >> 6;
    const int wm = (wave & 1) * 64, wn = (wave >> 1) * 64;
    const int quad = lane >> 4, l16 = lane & 15;

    // staging map: thread tid stages 16B at tile elements [tid*8 .. tid*8+8) (+2048 for 2nd issue)
    const int eoff = tid * 8;
    const int rowS = eoff >> 5;            // 0..63
    const int colS = eoff & 31;
    const __bf16* ga0 = A + (size_t)(m0 + rowS) * K + colS;
    const __bf16* ga1 = ga0 + (size_t)64 * K;
    const __bf16* gb0 = W + (size_t)(n0 + rowS) * K + colS;
    const __bf16* gb1 = gb0 + (size_t)64 * K;
    __bf16* lA0 = As + (tid & 192) * 8;    // wave-uniform LDS base
    __bf16* lA1 = lA0 + 2048;
    __bf16* lB0 = Bs + (tid & 192) * 8;
    __bf16* lB1 = lB0 + 2048;

    floatx4 acc[4][4] = {};

    for (int k0 = 0; k0 < K; k0 += 32) {
        gload_lds16(ga0 + k0, lA0);
        gload_lds16(ga1 + k0, lA1);
        gload_lds16(gb0 + k0, lB0);
        gload_lds16(gb1 + k0, lB1);
        __syncthreads();   // compiler emits vmcnt(0) drain before barrier

        bf16x8 af[4], bg[4];
#pragma unroll
        for (int i = 0; i < 4; ++i) {
            af[i] = *(const bf16x8*)(As + (wm + i * 16 + l16) * 32 + quad * 8);
            bg[i] = *(const bf16x8*)(Bs + (wn + i * 16 + l16) * 32 + quad * 8);
        }
#pragma unroll
        for (int i = 0; i < 4; ++i)
#pragma unroll
            for (int j = 0; j < 4; ++j)
                acc[i][j] = __builtin_amdgcn_mfma_f32_16x16x32_bf16(af[i], bg[j], acc[i][j], 0, 0, 0);
        __syncthreads();   // protect LDS from next iteration's staging
    }

    // Epilogue. C/D layout: col = lane&15, row = quad*4 + r  (m89-verified)
#pragma unroll
    for (int j = 0; j < 4; ++j) {
        const int n = n0 + wn + j * 16 + l16;
        const float bv = (n < Nreal) ? bias[n] : 0.0f;
#pragma unroll
        for (int i = 0; i < 4; ++i) {
#pragma unroll
            for (int r = 0; r < 4; ++r) {
                const int m = m0 + wm + i * 16 + quad * 4 + r;
                float v = acc[i][j][r] + bv;
                if (relu) v = fmaxf(v, 0.0f);
                if (outb) {
                    outb[(size_t)m * Npad + n] = (__bf16)v;
                } else if (n < Nreal) {
                    outf[(size_t)m * Nreal + n] = v;
                }
            }
        }
    }
}

extern "C" void kernel_launch(void* const* d_in, const int* in_sizes, int n_in,
                              void* d_out, int out_size, void* d_ws, size_t ws_size,
                              hipStream_t stream) {
    const float* x   = (const float*)d_in[0];
    const float* h0  = (const float*)d_in[1];
    const float* Wih = (const float*)d_in[2];
    const float* Whh = (const float*)d_in[3];
    const float* bih = (const float*)d_in[4];
    const float* bhh = (const float*)d_in[5];
    const float* w1  = (const float*)d_in[6];
    const float* b1  = (const float*)d_in[7];
    const float* w2  = (const float*)d_in[8];
    const float* b2  = (const float*)d_in[9];
    const float* w3  = (const float*)d_in[10];
    const float* b3  = (const float*)d_in[11];
    const float* w4  = (const float*)d_in[12];
    const float* b4  = (const float*)d_in[13];
    float* out = (float*)d_out;
    char* ws = (char*)d_ws;

    // workspace layout (bytes); xw aliases A1+A2 (dead before GEMM1 writes A1)
    __bf16* w1b = (__bf16*)(ws + 0);          //  1,376,256
    __bf16* w2b = (__bf16*)(ws + 1376256);    //  1,048,576
    __bf16* w3b = (__bf16*)(ws + 2424832);    //    131,072
    __bf16* w4b = (__bf16*)(ws + 2555904);    //    196,608
    __bf16* A0  = (__bf16*)(ws + 2752512);    // 11,010,048  [B, TP]
    __bf16* A1  = (__bf16*)(ws + 13762560);   // 16,777,216  [B, D1]
    __bf16* A2  = (__bf16*)(ws + 30539776);   //  8,388,608  [B, D2]
    __bf16* A3  = (__bf16*)(ws + 38928384);   //  2,097,152  [B, D3]
    float*  xw  = (float*) (ws + 13762560);   // 21,561,344  [B, T] (alias)

    convert_weights<<<5376, 256, 0, stream>>>(w1, w2, w3, w4, w1b, w2b, w3b, w4b);
    xw_kernel<<<21056, 256, 0, stream>>>(x, Wih, bih, xw);
    scan_kernel<<<32, 256, 0, stream>>>(xw, h0, Whh, bhh, A0, out + (size_t)B_ * T_);

    gemm_bt<<<dim3(64, 8), 256, 0, stream>>>(A0, w1b, b1, A1, nullptr, TP,  D1_, D1_, 1);
    gemm_bt<<<dim3(64, 4), 256, 0, stream>>>(A1, w2b, b2, A2, nullptr, D1_, D2_, D2_, 1);
    gemm_bt<<<dim3(64, 1), 256, 0, stream>>>(A2, w3b, b3, A3, nullptr, D2_, D3_, D3_, 1);
    gemm_bt<<<dim3(64, 6), 256, 0, stream>>>(A3, w4b, b4, nullptr, out, D3_, NP4, T_, 0);
}

// Round 3
// 352.365 us; speedup vs baseline: 1.8408x; 1.8408x over previous
//
#include <hip/hip_runtime.h>
#include <hip/hip_bf16.h>
#include <stdint.h>
#include <stddef.h>

#define B_  8192
#define T_  658
#define I_  7
#define TP  672     // T padded to multiple of 32 (GEMM1 K, xw row stride)
#define D1_ 1024
#define D2_ 512
#define D3_ 128
#define NP4 768     // T padded to multiple of 128 (GEMM4 N)

// scan kernel geometry
#define NB  64      // batch rows per block
#define CT  32      // timesteps per chunk
#define NCH 21      // TP / CT

typedef __bf16 bf16x8 __attribute__((ext_vector_type(8)));
typedef float  floatx4 __attribute__((ext_vector_type(4)));

__device__ __forceinline__ void gload_lds16(const void* g, void* l) {
    __builtin_amdgcn_global_load_lds(
        (const __attribute__((address_space(1))) void*)g,
        (__attribute__((address_space(3))) void*)l, 16, 0, 0);
}

__device__ __forceinline__ unsigned int pack_bf16x2(float a, float b) {
    unsigned int ua = __float_as_uint(a);
    unsigned int ub = __float_as_uint(b);
    ua += 0x7fffu + ((ua >> 16) & 1u);   // RNE to bf16 (finite inputs, |v|<=1)
    ub += 0x7fffu + ((ub >> 16) & 1u);
    return (ua >> 16) | (ub & 0xffff0000u);
}

// ---------------- Kernel 1: xw[b,t] = sum_i x[b,t,i]*Wih[i] + bih ------------
// xw is [B, TP] fp32, pad cols (t >= T_) written 0. Grid covers B*TP exactly.
__global__ void xw_kernel(const float* __restrict__ x,
                          const float* __restrict__ Wih,
                          const float* __restrict__ bih,
                          float* __restrict__ xw) {
    const int i = blockIdx.x * 256 + threadIdx.x;   // over B*TP
    const int b = i / TP, t = i - b * TP;
    float s = 0.0f;
    if (t < T_) {
        const float* xp = x + ((size_t)b * T_ + t) * I_;
        s = bih[0];
#pragma unroll
        for (int j = 0; j < I_; ++j) s = fmaf(xp[j], Wih[j], s);
    }
    xw[i] = s;
}

// ---------------- Kernel 2: chunked LDS-transpose tanh scan ------------------
// 128 blocks x 64 threads; block handles NB=64 batch rows; per chunk of CT=32
// timesteps: coalesced load -> LDS transpose -> 32 serial steps -> coalesced
// bf16 store of A0 [B, TP] (pad cols written 0). hlast fp32 [B].
__global__ __launch_bounds__(64) void scan_kernel(
    const float* __restrict__ xw, const float* __restrict__ h0,
    const float* __restrict__ Whh, const float* __restrict__ bhh,
    __bf16* __restrict__ A0, float* __restrict__ hlast) {
    __shared__ float        lds_x[CT * (NB + 1)];   // [t][b], pad -> conflict-free
    __shared__ unsigned int lds_o[NB * 17];          // [b][16 packed words + pad]

    const int tid = threadIdx.x;
    const int b0 = blockIdx.x * NB;
    const float whh = Whh[0], bh = bhh[0];
    const float C2L = 2.8853900817779268f;           // 2*log2(e)
    const float whhc = whh * C2L;
    float h = h0[b0 + tid];

    floatx4 pf[8];
    unsigned int res[CT / 2];

    // prologue: load chunk 0
#pragma unroll
    for (int l = 0; l < 8; ++l) {
        const int idx = l * NB + tid;
        const int bl = idx >> 3, q = idx & 7;
        pf[l] = *(const floatx4*)(xw + (size_t)(b0 + bl) * TP + q * 4);
    }

    for (int c = 0; c < NCH; ++c) {
        const int t0 = c * CT;
        __syncthreads();
        // transpose pf -> lds_x; stage prev chunk's results -> lds_o
#pragma unroll
        for (int l = 0; l < 8; ++l) {
            const int idx = l * NB + tid;
            const int bl = idx >> 3, q = idx & 7;
            lds_x[(q * 4 + 0) * (NB + 1) + bl] = pf[l][0];
            lds_x[(q * 4 + 1) * (NB + 1) + bl] = pf[l][1];
            lds_x[(q * 4 + 2) * (NB + 1) + bl] = pf[l][2];
            lds_x[(q * 4 + 3) * (NB + 1) + bl] = pf[l][3];
        }
        if (c > 0) {
#pragma unroll
            for (int j = 0; j < 16; ++j) lds_o[tid * 17 + j] = res[j];
        }
        __syncthreads();
        // coop store chunk c-1 (full 64B line per row)
        if (c > 0) {
            const int tprev = t0 - CT;
#pragma unroll
            for (int l = 0; l < 4; ++l) {
                const int idx = l * NB + tid;
                const int bl = idx >> 2, q = idx & 3;
                uint4 v;
                v.x = lds_o[bl * 17 + q * 4 + 0];
                v.y = lds_o[bl * 17 + q * 4 + 1];
                v.z = lds_o[bl * 17 + q * 4 + 2];
                v.w = lds_o[bl * 17 + q * 4 + 3];
                *(uint4*)(A0 + (size_t)(b0 + bl) * TP + tprev + q * 8) = v;
            }
        }
        // prefetch chunk c+1 (xw rows are TP long -> no clamp, no shift;
        // pad values (t >= T_) are loaded but never read by the compute loop)
        if (c + 1 < NCH) {
            const int tn = t0 + CT;
#pragma unroll
            for (int l = 0; l < 8; ++l) {
                const int idx = l * NB + tid;
                const int bl = idx >> 3, q = idx & 7;
                pf[l] = *(const floatx4*)(xw + (size_t)(b0 + bl) * TP + tn + q * 4);
            }
        }
        // compute: serial tanh chain, conflict-free LDS reads
        if (c < NCH - 1) {
#pragma unroll
            for (int k = 0; k < CT; k += 2) {
                float xv0 = lds_x[k * (NB + 1) + tid];
                float xv1 = lds_x[(k + 1) * (NB + 1) + tid];
                float e0 = __builtin_amdgcn_exp2f(fmaf(h, whhc, (xv0 + bh) * C2L));
                h = fmaf(-2.0f, __builtin_amdgcn_rcpf(e0 + 1.0f), 1.0f);
                float r0 = h;
                float e1 = __builtin_amdgcn_exp2f(fmaf(h, whhc, (xv1 + bh) * C2L));
                h = fmaf(-2.0f, __builtin_amdgcn_rcpf(e1 + 1.0f), 1.0f);
                res[k >> 1] = pack_bf16x2(r0, h);
            }
        } else {
            const int nval = T_ - t0;   // 18 on the last chunk
#pragma unroll
            for (int k = 0; k < CT; k += 2) {
                float r0 = 0.0f, r1 = 0.0f;
                if (k < nval) {
                    float xv0 = lds_x[k * (NB + 1) + tid];
                    float e0 = __builtin_amdgcn_exp2f(fmaf(h, whhc, (xv0 + bh) * C2L));
                    h = fmaf(-2.0f, __builtin_amdgcn_rcpf(e0 + 1.0f), 1.0f);
                    r0 = h;
                }
                if (k + 1 < nval) {
                    float xv1 = lds_x[(k + 1) * (NB + 1) + tid];
                    float e1 = __builtin_amdgcn_exp2f(fmaf(h, whhc, (xv1 + bh) * C2L));
                    h = fmaf(-2.0f, __builtin_amdgcn_rcpf(e1 + 1.0f), 1.0f);
                    r1 = h;
                }
                res[k >> 1] = pack_bf16x2(r0, r1);
            }
        }
    }
    // epilogue: store chunk NCH-1
    __syncthreads();
#pragma unroll
    for (int j = 0; j < 16; ++j) lds_o[tid * 17 + j] = res[j];
    __syncthreads();
    {
        const int tprev = TP - CT;
#pragma unroll
        for (int l = 0; l < 4; ++l) {
            const int idx = l * NB + tid;
            const int bl = idx >> 2, q = idx & 3;
            uint4 v;
            v.x = lds_o[bl * 17 + q * 4 + 0];
            v.y = lds_o[bl * 17 + q * 4 + 1];
            v.z = lds_o[bl * 17 + q * 4 + 2];
            v.w = lds_o[bl * 17 + q * 4 + 3];
            *(uint4*)(A0 + (size_t)(b0 + bl) * TP + tprev + q * 8) = v;
        }
    }
    hlast[b0 + tid] = h;
}

// ---------------- Kernel 3: fp32 -> bf16 weight conversion (with padding) ----
__global__ void convert_weights(const float* __restrict__ w1, const float* __restrict__ w2,
                                const float* __restrict__ w3, const float* __restrict__ w4,
                                __bf16* __restrict__ w1b, __bf16* __restrict__ w2b,
                                __bf16* __restrict__ w3b, __bf16* __restrict__ w4b) {
    int i = blockIdx.x * 256 + threadIdx.x;
    if (i < D1_ * TP) {
        int r = i / TP, c = i - r * TP;
        w1b[i] = (__bf16)(c < T_ ? w1[r * T_ + c] : 0.0f);
        return;
    }
    i -= D1_ * TP;
    if (i < D2_ * D1_) { w2b[i] = (__bf16)w2[i]; return; }
    i -= D2_ * D1_;
    if (i < D3_ * D2_) { w3b[i] = (__bf16)w3[i]; return; }
    i -= D3_ * D2_;
    {   // NP4*D3 elements
        int r = i / D3_, c = i - r * D3_;
        w4b[i] = (__bf16)(r < T_ ? w4[r * D3_ + c] : 0.0f);
    }
}

// ---------------- Kernel 4: bf16 MFMA GEMM, C = relu(A @ W^T + bias) ---------
__global__ __launch_bounds__(256, 2) void gemm_bt(
    const __bf16* __restrict__ A, const __bf16* __restrict__ W,
    const float* __restrict__ bias, __bf16* __restrict__ outb,
    float* __restrict__ outf, int K, int Npad, int Nreal, int relu) {
    __shared__ __align__(16) __bf16 As[128 * 32];
    __shared__ __align__(16) __bf16 Bs[128 * 32];

    const int tid = threadIdx.x;
    const int m0 = blockIdx.x * 128, n0 = blockIdx.y * 128;
    const int lane = tid & 63, wave = tid >> 6;
    const int wm = (wave & 1) * 64, wn = (wave >> 1) * 64;
    const int quad = lane >> 4, l16 = lane & 15;

    const int eoff = tid * 8;
    const int rowS = eoff >> 5;
    const int colS = eoff & 31;
    const __bf16* ga0 = A + (size_t)(m0 + rowS) * K + colS;
    const __bf16* ga1 = ga0 + (size_t)64 * K;
    const __bf16* gb0 = W + (size_t)(n0 + rowS) * K + colS;
    const __bf16* gb1 = gb0 + (size_t)64 * K;
    __bf16* lA0 = As + (tid & 192) * 8;
    __bf16* lA1 = lA0 + 2048;
    __bf16* lB0 = Bs + (tid & 192) * 8;
    __bf16* lB1 = lB0 + 2048;

    floatx4 acc[4][4] = {};

    for (int k0 = 0; k0 < K; k0 += 32) {
        gload_lds16(ga0 + k0, lA0);
        gload_lds16(ga1 + k0, lA1);
        gload_lds16(gb0 + k0, lB0);
        gload_lds16(gb1 + k0, lB1);
        __syncthreads();

        bf16x8 af[4], bg[4];
#pragma unroll
        for (int i = 0; i < 4; ++i) {
            af[i] = *(const bf16x8*)(As + (wm + i * 16 + l16) * 32 + quad * 8);
            bg[i] = *(const bf16x8*)(Bs + (wn + i * 16 + l16) * 32 + quad * 8);
        }
#pragma unroll
        for (int i = 0; i < 4; ++i)
#pragma unroll
            for (int j = 0; j < 4; ++j)
                acc[i][j] = __builtin_amdgcn_mfma_f32_16x16x32_bf16(af[i], bg[j], acc[i][j], 0, 0, 0);
        __syncthreads();
    }

#pragma unroll
    for (int j = 0; j < 4; ++j) {
        const int n = n0 + wn + j * 16 + l16;
        const float bv = (n < Nreal) ? bias[n] : 0.0f;
#pragma unroll
        for (int i = 0; i < 4; ++i) {
#pragma unroll
            for (int r = 0; r < 4; ++r) {
                const int m = m0 + wm + i * 16 + quad * 4 + r;
                float v = acc[i][j][r] + bv;
                if (relu) v = fmaxf(v, 0.0f);
                if (outb) {
                    outb[(size_t)m * Npad + n] = (__bf16)v;
                } else if (n < Nreal) {
                    outf[(size_t)m * Nreal + n] = v;
                }
            }
        }
    }
}

extern "C" void kernel_launch(void* const* d_in, const int* in_sizes, int n_in,
                              void* d_out, int out_size, void* d_ws, size_t ws_size,
                              hipStream_t stream) {
    const float* x   = (const float*)d_in[0];
    const float* h0  = (const float*)d_in[1];
    const float* Wih = (const float*)d_in[2];
    const float* Whh = (const float*)d_in[3];
    const float* bih = (const float*)d_in[4];
    const float* bhh = (const float*)d_in[5];
    const float* w1  = (const float*)d_in[6];
    const float* b1  = (const float*)d_in[7];
    const float* w2  = (const float*)d_in[8];
    const float* b2  = (const float*)d_in[9];
    const float* w3  = (const float*)d_in[10];
    const float* b3  = (const float*)d_in[11];
    const float* w4  = (const float*)d_in[12];
    const float* b4  = (const float*)d_in[13];
    float* out = (float*)d_out;
    char* ws = (char*)d_ws;

    __bf16* w1b = (__bf16*)(ws + 0);          //  1,376,256
    __bf16* w2b = (__bf16*)(ws + 1376256);    //  1,048,576
    __bf16* w3b = (__bf16*)(ws + 2424832);    //    131,072
    __bf16* w4b = (__bf16*)(ws + 2555904);    //    196,608
    __bf16* A0  = (__bf16*)(ws + 2752512);    // 11,010,048  [B, TP]
    __bf16* A1  = (__bf16*)(ws + 13762560);   // 16,777,216  [B, D1]
    __bf16* A2  = (__bf16*)(ws + 30539776);   //  8,388,608  [B, D2]
    __bf16* A3  = (__bf16*)(ws + 38928384);   //  2,097,152  [B, D3]
    float*  xw  = (float*) (ws + 13762560);   // 22,020,096  [B, TP] (aliases A1+A2)

    convert_weights<<<5376, 256, 0, stream>>>(w1, w2, w3, w4, w1b, w2b, w3b, w4b);
    xw_kernel<<<21504, 256, 0, stream>>>(x, Wih, bih, xw);
    scan_kernel<<<128, 64, 0, stream>>>(xw, h0, Whh, bhh, A0, out + (size_t)B_ * T_);

    gemm_bt<<<dim3(64, 8), 256, 0, stream>>>(A0, w1b, b1, A1, nullptr, TP,  D1_, D1_, 1);
    gemm_bt<<<dim3(64, 4), 256, 0, stream>>>(A1, w2b, b2, A2, nullptr, D1_, D2_, D2_, 1);
    gemm_bt<<<dim3(64, 1), 256, 0, stream>>>(A2, w3b, b3, A3, nullptr, D2_, D3_, D3_, 1);
    gemm_bt<<<dim3(64, 6), 256, 0, stream>>>(A3, w4b, b4, nullptr, out, D3_, NP4, T_, 0);
}

// Round 4
// 342.158 us; speedup vs baseline: 1.8957x; 1.0298x over previous
//
#include <hip/hip_runtime.h>
#include <hip/hip_bf16.h>
#include <stdint.h>
#include <stddef.h>

#define B_  8192
#define T_  658
#define I_  7
#define TP  672     // T padded to multiple of 32 (GEMM1 K, xw row stride)
#define D1_ 1024
#define D2_ 512
#define D3_ 128
#define NP4 768     // T padded to multiple of 128 (GEMM4 N)

// scan kernel geometry
#define NB  64      // batch rows per block
#define CT  32      // timesteps per chunk
#define NCH 21      // TP / CT

typedef __bf16 bf16x8 __attribute__((ext_vector_type(8)));
typedef float  floatx4 __attribute__((ext_vector_type(4)));

__device__ __forceinline__ void gload_lds16(const void* g, void* l) {
    __builtin_amdgcn_global_load_lds(
        (const __attribute__((address_space(1))) void*)g,
        (__attribute__((address_space(3))) void*)l, 16, 0, 0);
}

__device__ __forceinline__ unsigned int pack_bf16x2(float a, float b) {
    unsigned int ua = __float_as_uint(a);
    unsigned int ub = __float_as_uint(b);
    ua += 0x7fffu + ((ua >> 16) & 1u);   // RNE to bf16 (finite inputs, |v|<=1)
    ub += 0x7fffu + ((ub >> 16) & 1u);
    return (ua >> 16) | (ub & 0xffff0000u);
}

__device__ __forceinline__ float bf16lo(unsigned int u) { return __uint_as_float(u << 16); }
__device__ __forceinline__ float bf16hi(unsigned int u) { return __uint_as_float(u & 0xffff0000u); }

// ---------------- Kernel 1: xw[b,t] = sum_i x[b,t,i]*Wih[i] + bih ------------
// xwb is [B, TP] bf16, pad cols (t >= T_) written 0. Grid covers B*TP exactly.
__global__ void xw_kernel(const float* __restrict__ x,
                          const float* __restrict__ Wih,
                          const float* __restrict__ bih,
                          __bf16* __restrict__ xwb) {
    const int i = blockIdx.x * 256 + threadIdx.x;   // over B*TP
    const int b = i / TP, t = i - b * TP;
    float s = 0.0f;
    if (t < T_) {
        const float* xp = x + ((size_t)b * T_ + t) * I_;
        s = bih[0];
#pragma unroll
        for (int j = 0; j < I_; ++j) s = fmaf(xp[j], Wih[j], s);
    }
    xwb[i] = (__bf16)s;
}

// ---------------- Kernel 2: chunked LDS-transpose tanh scan ------------------
// 128 blocks x 64 threads; block handles NB=64 batch rows; per chunk of CT=32
// timesteps: coalesced bf16 load -> LDS transpose -> 32 serial steps ->
// coalesced bf16 store of A0 [B, TP] (pad cols 0). hlast fp32 [B].
__global__ __launch_bounds__(64) void scan_kernel(
    const __bf16* __restrict__ xwb, const float* __restrict__ h0,
    const float* __restrict__ Whh, const float* __restrict__ bhh,
    __bf16* __restrict__ A0, float* __restrict__ hlast) {
    __shared__ float        lds_x[CT * (NB + 1)];   // [t][b], pad -> <=2-way (free)
    __shared__ unsigned int lds_o[NB * 17];          // [b][16 packed words + pad]

    const int tid = threadIdx.x;
    const int b0 = blockIdx.x * NB;
    const float whh = Whh[0], bh = bhh[0];
    const float C2L = 2.8853900817779268f;           // 2*log2(e)
    const float whhc = whh * C2L;
    float h = h0[b0 + tid];

    uint4 pf[4];
    unsigned int res[CT / 2];

    // prologue: load chunk 0 (each uint4 = 8 consecutive t of one row)
#pragma unroll
    for (int l = 0; l < 4; ++l) {
        const int idx = l * NB + tid;
        const int bl = idx >> 2, q = idx & 3;
        pf[l] = *(const uint4*)(xwb + (size_t)(b0 + bl) * TP + q * 8);
    }

    for (int c = 0; c < NCH; ++c) {
        const int t0 = c * CT;
        __syncthreads();
        // transpose+unpack pf -> lds_x; stage prev chunk's results -> lds_o
#pragma unroll
        for (int l = 0; l < 4; ++l) {
            const int idx = l * NB + tid;
            const int bl = idx >> 2, q = idx & 3;
            const uint4 v = pf[l];
            lds_x[(q * 8 + 0) * (NB + 1) + bl] = bf16lo(v.x);
            lds_x[(q * 8 + 1) * (NB + 1) + bl] = bf16hi(v.x);
            lds_x[(q * 8 + 2) * (NB + 1) + bl] = bf16lo(v.y);
            lds_x[(q * 8 + 3) * (NB + 1) + bl] = bf16hi(v.y);
            lds_x[(q * 8 + 4) * (NB + 1) + bl] = bf16lo(v.z);
            lds_x[(q * 8 + 5) * (NB + 1) + bl] = bf16hi(v.z);
            lds_x[(q * 8 + 6) * (NB + 1) + bl] = bf16lo(v.w);
            lds_x[(q * 8 + 7) * (NB + 1) + bl] = bf16hi(v.w);
        }
        if (c > 0) {
#pragma unroll
            for (int j = 0; j < 16; ++j) lds_o[tid * 17 + j] = res[j];
        }
        __syncthreads();
        // coop store chunk c-1 (full 64B line per row)
        if (c > 0) {
            const int tprev = t0 - CT;
#pragma unroll
            for (int l = 0; l < 4; ++l) {
                const int idx = l * NB + tid;
                const int bl = idx >> 2, q = idx & 3;
                uint4 v;
                v.x = lds_o[bl * 17 + q * 4 + 0];
                v.y = lds_o[bl * 17 + q * 4 + 1];
                v.z = lds_o[bl * 17 + q * 4 + 2];
                v.w = lds_o[bl * 17 + q * 4 + 3];
                *(uint4*)(A0 + (size_t)(b0 + bl) * TP + tprev + q * 8) = v;
            }
        }
        // prefetch chunk c+1 (rows are TP long; pad bf16 values never consumed)
        if (c + 1 < NCH) {
            const int tn = t0 + CT;
#pragma unroll
            for (int l = 0; l < 4; ++l) {
                const int idx = l * NB + tid;
                const int bl = idx >> 2, q = idx & 3;
                pf[l] = *(const uint4*)(xwb + (size_t)(b0 + bl) * TP + tn + q * 8);
            }
        }
        // compute: serial tanh chain, conflict-free LDS reads
        if (c < NCH - 1) {
#pragma unroll
            for (int k = 0; k < CT; k += 2) {
                float xv0 = lds_x[k * (NB + 1) + tid];
                float xv1 = lds_x[(k + 1) * (NB + 1) + tid];
                float e0 = __builtin_amdgcn_exp2f(fmaf(h, whhc, (xv0 + bh) * C2L));
                h = fmaf(-2.0f, __builtin_amdgcn_rcpf(e0 + 1.0f), 1.0f);
                float r0 = h;
                float e1 = __builtin_amdgcn_exp2f(fmaf(h, whhc, (xv1 + bh) * C2L));
                h = fmaf(-2.0f, __builtin_amdgcn_rcpf(e1 + 1.0f), 1.0f);
                res[k >> 1] = pack_bf16x2(r0, h);
            }
        } else {
            const int nval = T_ - t0;   // 18 on the last chunk
#pragma unroll
            for (int k = 0; k < CT; k += 2) {
                float r0 = 0.0f, r1 = 0.0f;
                if (k < nval) {
                    float xv0 = lds_x[k * (NB + 1) + tid];
                    float e0 = __builtin_amdgcn_exp2f(fmaf(h, whhc, (xv0 + bh) * C2L));
                    h = fmaf(-2.0f, __builtin_amdgcn_rcpf(e0 + 1.0f), 1.0f);
                    r0 = h;
                }
                if (k + 1 < nval) {
                    float xv1 = lds_x[(k + 1) * (NB + 1) + tid];
                    float e1 = __builtin_amdgcn_exp2f(fmaf(h, whhc, (xv1 + bh) * C2L));
                    h = fmaf(-2.0f, __builtin_amdgcn_rcpf(e1 + 1.0f), 1.0f);
                    r1 = h;
                }
                res[k >> 1] = pack_bf16x2(r0, r1);
            }
        }
    }
    // epilogue: store chunk NCH-1
    __syncthreads();
#pragma unroll
    for (int j = 0; j < 16; ++j) lds_o[tid * 17 + j] = res[j];
    __syncthreads();
    {
        const int tprev = TP - CT;
#pragma unroll
        for (int l = 0; l < 4; ++l) {
            const int idx = l * NB + tid;
            const int bl = idx >> 2, q = idx & 3;
            uint4 v;
            v.x = lds_o[bl * 17 + q * 4 + 0];
            v.y = lds_o[bl * 17 + q * 4 + 1];
            v.z = lds_o[bl * 17 + q * 4 + 2];
            v.w = lds_o[bl * 17 + q * 4 + 3];
            *(uint4*)(A0 + (size_t)(b0 + bl) * TP + tprev + q * 8) = v;
        }
    }
    hlast[b0 + tid] = h;
}

// ---------------- Kernel 3: fp32 -> bf16 weight conversion (with padding) ----
__global__ void convert_weights(const float* __restrict__ w1, const float* __restrict__ w2,
                                const float* __restrict__ w3, const float* __restrict__ w4,
                                __bf16* __restrict__ w1b, __bf16* __restrict__ w2b,
                                __bf16* __restrict__ w3b, __bf16* __restrict__ w4b) {
    int i = blockIdx.x * 256 + threadIdx.x;
    if (i < D1_ * TP) {
        int r = i / TP, c = i - r * TP;
        w1b[i] = (__bf16)(c < T_ ? w1[r * T_ + c] : 0.0f);
        return;
    }
    i -= D1_ * TP;
    if (i < D2_ * D1_) { w2b[i] = (__bf16)w2[i]; return; }
    i -= D2_ * D1_;
    if (i < D3_ * D2_) { w3b[i] = (__bf16)w3[i]; return; }
    i -= D3_ * D2_;
    {   // NP4*D3 elements
        int r = i / D3_, c = i - r * D3_;
        w4b[i] = (__bf16)(r < T_ ? w4[r * D3_ + c] : 0.0f);
    }
}

// ---------------- Kernel 4: bf16 MFMA GEMM, C = relu(A @ W^T + bias) ---------
// BM x 128 tile, BK=32, 256 threads. BM=128: waves 2x2 over (64m,64n), acc 4x4.
// BM=64: waves 2x2 over (32m,64n), acc 2x4 -> 2x the blocks for small GEMMs.
template<int BM>
__global__ __launch_bounds__(256, 2) void gemm_bt(
    const __bf16* __restrict__ A, const __bf16* __restrict__ W,
    const float* __restrict__ bias, __bf16* __restrict__ outb,
    float* __restrict__ outf, int K, int Npad, int Nreal, int relu) {
    constexpr int MI = BM / 32;   // m fragments per wave
    constexpr int nA = BM / 64;   // 16B staging issues per thread for A
    __shared__ __align__(16) __bf16 As[BM * 32];
    __shared__ __align__(16) __bf16 Bs[128 * 32];

    const int tid = threadIdx.x;
    const int m0 = blockIdx.x * BM, n0 = blockIdx.y * 128;
    const int lane = tid & 63, wave = tid >> 6;
    const int wm = (wave & 1) * (BM / 2), wn = (wave >> 1) * 64;
    const int quad = lane >> 4, l16 = lane & 15;

    const int eoff = tid * 8;
    const int rowS = eoff >> 5;            // 0..63
    const int colS = eoff & 31;
    const __bf16* gb0 = W + (size_t)(n0 + rowS) * K + colS;
    const __bf16* gb1 = gb0 + (size_t)64 * K;
    __bf16* lB0 = Bs + (tid & 192) * 8;
    __bf16* lB1 = lB0 + 2048;
    const __bf16* gaa[nA];
    __bf16* laa[nA];
#pragma unroll
    for (int c = 0; c < nA; ++c) {
        gaa[c] = A + (size_t)(m0 + rowS + c * 64) * K + colS;
        laa[c] = As + c * 2048 + (tid & 192) * 8;
    }

    floatx4 acc[MI][4] = {};

    for (int k0 = 0; k0 < K; k0 += 32) {
#pragma unroll
        for (int c = 0; c < nA; ++c) gload_lds16(gaa[c] + k0, laa[c]);
        gload_lds16(gb0 + k0, lB0);
        gload_lds16(gb1 + k0, lB1);
        __syncthreads();

        bf16x8 af[MI], bg[4];
#pragma unroll
        for (int i = 0; i < MI; ++i)
            af[i] = *(const bf16x8*)(As + (wm + i * 16 + l16) * 32 + quad * 8);
#pragma unroll
        for (int j = 0; j < 4; ++j)
            bg[j] = *(const bf16x8*)(Bs + (wn + j * 16 + l16) * 32 + quad * 8);
#pragma unroll
        for (int i = 0; i < MI; ++i)
#pragma unroll
            for (int j = 0; j < 4; ++j)
                acc[i][j] = __builtin_amdgcn_mfma_f32_16x16x32_bf16(af[i], bg[j], acc[i][j], 0, 0, 0);
        __syncthreads();
    }

    // Epilogue. C/D layout: col = lane&15, row = quad*4 + r (m89-verified)
#pragma unroll
    for (int j = 0; j < 4; ++j) {
        const int n = n0 + wn + j * 16 + l16;
        const float bv = (n < Nreal) ? bias[n] : 0.0f;
#pragma unroll
        for (int i = 0; i < MI; ++i) {
#pragma unroll
            for (int r = 0; r < 4; ++r) {
                const int m = m0 + wm + i * 16 + quad * 4 + r;
                float v = acc[i][j][r] + bv;
                if (relu) v = fmaxf(v, 0.0f);
                if (outb) {
                    outb[(size_t)m * Npad + n] = (__bf16)v;
                } else if (n < Nreal) {
                    outf[(size_t)m * Nreal + n] = v;
                }
            }
        }
    }
}

extern "C" void kernel_launch(void* const* d_in, const int* in_sizes, int n_in,
                              void* d_out, int out_size, void* d_ws, size_t ws_size,
                              hipStream_t stream) {
    const float* x   = (const float*)d_in[0];
    const float* h0  = (const float*)d_in[1];
    const float* Wih = (const float*)d_in[2];
    const float* Whh = (const float*)d_in[3];
    const float* bih = (const float*)d_in[4];
    const float* bhh = (const float*)d_in[5];
    const float* w1  = (const float*)d_in[6];
    const float* b1  = (const float*)d_in[7];
    const float* w2  = (const float*)d_in[8];
    const float* b2  = (const float*)d_in[9];
    const float* w3  = (const float*)d_in[10];
    const float* b3  = (const float*)d_in[11];
    const float* w4  = (const float*)d_in[12];
    const float* b4  = (const float*)d_in[13];
    float* out = (float*)d_out;
    char* ws = (char*)d_ws;

    __bf16* w1b = (__bf16*)(ws + 0);          //  1,376,256
    __bf16* w2b = (__bf16*)(ws + 1376256);    //  1,048,576
    __bf16* w3b = (__bf16*)(ws + 2424832);    //    131,072
    __bf16* w4b = (__bf16*)(ws + 2555904);    //    196,608
    __bf16* A0  = (__bf16*)(ws + 2752512);    // 11,010,048  [B, TP]
    __bf16* A1  = (__bf16*)(ws + 13762560);   // 16,777,216  [B, D1]
    __bf16* A2  = (__bf16*)(ws + 30539776);   //  8,388,608  [B, D2]
    __bf16* A3  = (__bf16*)(ws + 38928384);   //  2,097,152  [B, D3]
    __bf16* xwb = (__bf16*)(ws + 13762560);   // 11,010,048  [B, TP] (aliases A1; dead before GEMM1)

    convert_weights<<<5376, 256, 0, stream>>>(w1, w2, w3, w4, w1b, w2b, w3b, w4b);
    xw_kernel<<<21504, 256, 0, stream>>>(x, Wih, bih, xwb);
    scan_kernel<<<128, 64, 0, stream>>>(xwb, h0, Whh, bhh, A0, out + (size_t)B_ * T_);

    gemm_bt<128><<<dim3(64, 8),  256, 0, stream>>>(A0, w1b, b1, A1, nullptr, TP,  D1_, D1_, 1);
    gemm_bt<64> <<<dim3(128, 4), 256, 0, stream>>>(A1, w2b, b2, A2, nullptr, D1_, D2_, D2_, 1);
    gemm_bt<64> <<<dim3(128, 1), 256, 0, stream>>>(A2, w3b, b3, A3, nullptr, D2_, D3_, D3_, 1);
    gemm_bt<128><<<dim3(64, 6),  256, 0, stream>>>(A3, w4b, b4, nullptr, out, D3_, NP4, T_, 0);
}

// Round 5
// 333.706 us; speedup vs baseline: 1.9437x; 1.0253x over previous
//
#include <hip/hip_runtime.h>
#include <hip/hip_bf16.h>
#include <stdint.h>
#include <stddef.h>

#define B_  8192
#define T_  658
#define I_  7
#define TP  672     // T padded to multiple of 32 (GEMM1 K, xw row stride)
#define D1_ 1024
#define D2_ 512
#define D3_ 128
#define NP4 768     // T padded to multiple of 128 (GEMM4 N)

// scan kernel geometry
#define NB  64      // batch rows per block
#define CT  32      // timesteps per chunk
#define NCH 21      // TP / CT

#define XWBLKS 21504            // B_*TP/256
#define CVBLKS 5376             // (D1_*TP + D2_*D1_ + D3_*D2_ + NP4*D3_)/256

typedef __bf16 bf16x8 __attribute__((ext_vector_type(8)));
typedef float  floatx4 __attribute__((ext_vector_type(4)));

__device__ __forceinline__ void gload_lds16(const void* g, void* l) {
    __builtin_amdgcn_global_load_lds(
        (const __attribute__((address_space(1))) void*)g,
        (__attribute__((address_space(3))) void*)l, 16, 0, 0);
}

__device__ __forceinline__ unsigned int pack_bf16x2(float a, float b) {
    unsigned int ua = __float_as_uint(a);
    unsigned int ub = __float_as_uint(b);
    ua += 0x7fffu + ((ua >> 16) & 1u);   // RNE to bf16 (finite inputs, |v|<=1)
    ub += 0x7fffu + ((ub >> 16) & 1u);
    return (ua >> 16) | (ub & 0xffff0000u);
}

__device__ __forceinline__ float bf16lo(unsigned int u) { return __uint_as_float(u << 16); }
__device__ __forceinline__ float bf16hi(unsigned int u) { return __uint_as_float(u & 0xffff0000u); }

// ------- Kernel 1 (fused): xw projection + fp32->bf16 weight conversion -----
// blocks [0, XWBLKS): xwb[b,t] = sum_i x[b,t,i]*Wih[i] + bih  (bf16 [B,TP])
// blocks [XWBLKS, XWBLKS+CVBLKS): convert w1..w4 to bf16 with padding
__global__ void xw_conv_kernel(const float* __restrict__ x,
                               const float* __restrict__ Wih,
                               const float* __restrict__ bih,
                               __bf16* __restrict__ xwb,
                               const float* __restrict__ w1, const float* __restrict__ w2,
                               const float* __restrict__ w3, const float* __restrict__ w4,
                               __bf16* __restrict__ w1b, __bf16* __restrict__ w2b,
                               __bf16* __restrict__ w3b, __bf16* __restrict__ w4b) {
    if (blockIdx.x < XWBLKS) {
        const int i = blockIdx.x * 256 + threadIdx.x;   // over B*TP
        const int b = i / TP, t = i - b * TP;
        float s = 0.0f;
        if (t < T_) {
            const float* xp = x + ((size_t)b * T_ + t) * I_;
            s = bih[0];
#pragma unroll
            for (int j = 0; j < I_; ++j) s = fmaf(xp[j], Wih[j], s);
        }
        xwb[i] = (__bf16)s;
        return;
    }
    int i = (blockIdx.x - XWBLKS) * 256 + threadIdx.x;
    if (i < D1_ * TP) {
        int r = i / TP, c = i - r * TP;
        w1b[i] = (__bf16)(c < T_ ? w1[r * T_ + c] : 0.0f);
        return;
    }
    i -= D1_ * TP;
    if (i < D2_ * D1_) { w2b[i] = (__bf16)w2[i]; return; }
    i -= D2_ * D1_;
    if (i < D3_ * D2_) { w3b[i] = (__bf16)w3[i]; return; }
    i -= D3_ * D2_;
    {   // NP4*D3 elements
        int r = i / D3_, c = i - r * D3_;
        w4b[i] = (__bf16)(r < T_ ? w4[r * D3_ + c] : 0.0f);
    }
}

// ---------------- Kernel 2: chunked LDS-transpose tanh scan ------------------
__global__ __launch_bounds__(64) void scan_kernel(
    const __bf16* __restrict__ xwb, const float* __restrict__ h0,
    const float* __restrict__ Whh, const float* __restrict__ bhh,
    __bf16* __restrict__ A0, float* __restrict__ hlast) {
    __shared__ float        lds_x[CT * (NB + 1)];   // [t][b], pad -> <=2-way (free)
    __shared__ unsigned int lds_o[NB * 17];          // [b][16 packed words + pad]

    const int tid = threadIdx.x;
    const int b0 = blockIdx.x * NB;
    const float whh = Whh[0], bh = bhh[0];
    const float C2L = 2.8853900817779268f;           // 2*log2(e)
    const float whhc = whh * C2L;
    float h = h0[b0 + tid];

    uint4 pf[4];
    unsigned int res[CT / 2];

#pragma unroll
    for (int l = 0; l < 4; ++l) {
        const int idx = l * NB + tid;
        const int bl = idx >> 2, q = idx & 3;
        pf[l] = *(const uint4*)(xwb + (size_t)(b0 + bl) * TP + q * 8);
    }

    for (int c = 0; c < NCH; ++c) {
        const int t0 = c * CT;
        __syncthreads();
#pragma unroll
        for (int l = 0; l < 4; ++l) {
            const int idx = l * NB + tid;
            const int bl = idx >> 2, q = idx & 3;
            const uint4 v = pf[l];
            lds_x[(q * 8 + 0) * (NB + 1) + bl] = bf16lo(v.x);
            lds_x[(q * 8 + 1) * (NB + 1) + bl] = bf16hi(v.x);
            lds_x[(q * 8 + 2) * (NB + 1) + bl] = bf16lo(v.y);
            lds_x[(q * 8 + 3) * (NB + 1) + bl] = bf16hi(v.y);
            lds_x[(q * 8 + 4) * (NB + 1) + bl] = bf16lo(v.z);
            lds_x[(q * 8 + 5) * (NB + 1) + bl] = bf16hi(v.z);
            lds_x[(q * 8 + 6) * (NB + 1) + bl] = bf16lo(v.w);
            lds_x[(q * 8 + 7) * (NB + 1) + bl] = bf16hi(v.w);
        }
        if (c > 0) {
#pragma unroll
            for (int j = 0; j < 16; ++j) lds_o[tid * 17 + j] = res[j];
        }
        __syncthreads();
        if (c > 0) {
            const int tprev = t0 - CT;
#pragma unroll
            for (int l = 0; l < 4; ++l) {
                const int idx = l * NB + tid;
                const int bl = idx >> 2, q = idx & 3;
                uint4 v;
                v.x = lds_o[bl * 17 + q * 4 + 0];
                v.y = lds_o[bl * 17 + q * 4 + 1];
                v.z = lds_o[bl * 17 + q * 4 + 2];
                v.w = lds_o[bl * 17 + q * 4 + 3];
                *(uint4*)(A0 + (size_t)(b0 + bl) * TP + tprev + q * 8) = v;
            }
        }
        if (c + 1 < NCH) {
            const int tn = t0 + CT;
#pragma unroll
            for (int l = 0; l < 4; ++l) {
                const int idx = l * NB + tid;
                const int bl = idx >> 2, q = idx & 3;
                pf[l] = *(const uint4*)(xwb + (size_t)(b0 + bl) * TP + tn + q * 8);
            }
        }
        if (c < NCH - 1) {
#pragma unroll
            for (int k = 0; k < CT; k += 2) {
                float xv0 = lds_x[k * (NB + 1) + tid];
                float xv1 = lds_x[(k + 1) * (NB + 1) + tid];
                float e0 = __builtin_amdgcn_exp2f(fmaf(h, whhc, (xv0 + bh) * C2L));
                h = fmaf(-2.0f, __builtin_amdgcn_rcpf(e0 + 1.0f), 1.0f);
                float r0 = h;
                float e1 = __builtin_amdgcn_exp2f(fmaf(h, whhc, (xv1 + bh) * C2L));
                h = fmaf(-2.0f, __builtin_amdgcn_rcpf(e1 + 1.0f), 1.0f);
                res[k >> 1] = pack_bf16x2(r0, h);
            }
        } else {
            const int nval = T_ - t0;   // 18 on the last chunk
#pragma unroll
            for (int k = 0; k < CT; k += 2) {
                float r0 = 0.0f, r1 = 0.0f;
                if (k < nval) {
                    float xv0 = lds_x[k * (NB + 1) + tid];
                    float e0 = __builtin_amdgcn_exp2f(fmaf(h, whhc, (xv0 + bh) * C2L));
                    h = fmaf(-2.0f, __builtin_amdgcn_rcpf(e0 + 1.0f), 1.0f);
                    r0 = h;
                }
                if (k + 1 < nval) {
                    float xv1 = lds_x[(k + 1) * (NB + 1) + tid];
                    float e1 = __builtin_amdgcn_exp2f(fmaf(h, whhc, (xv1 + bh) * C2L));
                    h = fmaf(-2.0f, __builtin_amdgcn_rcpf(e1 + 1.0f), 1.0f);
                    r1 = h;
                }
                res[k >> 1] = pack_bf16x2(r0, r1);
            }
        }
    }
    __syncthreads();
#pragma unroll
    for (int j = 0; j < 16; ++j) lds_o[tid * 17 + j] = res[j];
    __syncthreads();
    {
        const int tprev = TP - CT;
#pragma unroll
        for (int l = 0; l < 4; ++l) {
            const int idx = l * NB + tid;
            const int bl = idx >> 2, q = idx & 3;
            uint4 v;
            v.x = lds_o[bl * 17 + q * 4 + 0];
            v.y = lds_o[bl * 17 + q * 4 + 1];
            v.z = lds_o[bl * 17 + q * 4 + 2];
            v.w = lds_o[bl * 17 + q * 4 + 3];
            *(uint4*)(A0 + (size_t)(b0 + bl) * TP + tprev + q * 8) = v;
        }
    }
    hlast[b0 + tid] = h;
}

// ---------------- Kernel 3: bf16 MFMA GEMM, C = relu(A @ W^T + bias) ---------
// BM x BN tile, BK=32, 256 threads = 4 waves in 2x2; wave tile (BM/2)x(BN/2).
// Small tiles -> more blocks/CU (grid-size-limited GEMMs here).
template<int BM, int BN>
__global__ __launch_bounds__(256, 4) void gemm_bt(
    const __bf16* __restrict__ A, const __bf16* __restrict__ W,
    const float* __restrict__ bias, __bf16* __restrict__ outb,
    float* __restrict__ outf, int K, int Npad, int Nreal, int relu) {
    constexpr int MI = BM / 32;   // m fragments per wave
    constexpr int NJ = BN / 32;   // n fragments per wave
    constexpr int nA = BM / 64;   // 16B staging issues per thread, A tile
    constexpr int nB = BN / 64;   // 16B staging issues per thread, B tile
    __shared__ __align__(16) __bf16 As[BM * 32];
    __shared__ __align__(16) __bf16 Bs[BN * 32];

    const int tid = threadIdx.x;
    const int m0 = blockIdx.x * BM, n0 = blockIdx.y * BN;
    const int lane = tid & 63, wave = tid >> 6;
    const int wm = (wave & 1) * (BM / 2), wn = (wave >> 1) * (BN / 2);
    const int quad = lane >> 4, l16 = lane & 15;

    const int eoff = tid * 8;
    const int rowS = eoff >> 5;            // 0..63
    const int colS = eoff & 31;
    const __bf16* gaa[nA];
    const __bf16* gbb[nB];
    __bf16* laa[nA];
    __bf16* lbb[nB];
#pragma unroll
    for (int c = 0; c < nA; ++c) {
        gaa[c] = A + (size_t)(m0 + rowS + c * 64) * K + colS;
        laa[c] = As + c * 2048 + (tid & 192) * 8;   // wave-uniform base
    }
#pragma unroll
    for (int c = 0; c < nB; ++c) {
        gbb[c] = W + (size_t)(n0 + rowS + c * 64) * K + colS;
        lbb[c] = Bs + c * 2048 + (tid & 192) * 8;
    }

    floatx4 acc[MI][NJ] = {};

    for (int k0 = 0; k0 < K; k0 += 32) {
#pragma unroll
        for (int c = 0; c < nA; ++c) gload_lds16(gaa[c] + k0, laa[c]);
#pragma unroll
        for (int c = 0; c < nB; ++c) gload_lds16(gbb[c] + k0, lbb[c]);
        __syncthreads();

        bf16x8 af[MI], bg[NJ];
#pragma unroll
        for (int i = 0; i < MI; ++i)
            af[i] = *(const bf16x8*)(As + (wm + i * 16 + l16) * 32 + quad * 8);
#pragma unroll
        for (int j = 0; j < NJ; ++j)
            bg[j] = *(const bf16x8*)(Bs + (wn + j * 16 + l16) * 32 + quad * 8);
#pragma unroll
        for (int i = 0; i < MI; ++i)
#pragma unroll
            for (int j = 0; j < NJ; ++j)
                acc[i][j] = __builtin_amdgcn_mfma_f32_16x16x32_bf16(af[i], bg[j], acc[i][j], 0, 0, 0);
        __syncthreads();
    }

    // Epilogue. C/D layout: col = lane&15, row = quad*4 + r (m89-verified)
#pragma unroll
    for (int j = 0; j < NJ; ++j) {
        const int n = n0 + wn + j * 16 + l16;
        const float bv = (n < Nreal) ? bias[n] : 0.0f;
#pragma unroll
        for (int i = 0; i < MI; ++i) {
#pragma unroll
            for (int r = 0; r < 4; ++r) {
                const int m = m0 + wm + i * 16 + quad * 4 + r;
                float v = acc[i][j][r] + bv;
                if (relu) v = fmaxf(v, 0.0f);
                if (outb) {
                    outb[(size_t)m * Npad + n] = (__bf16)v;
                } else if (n < Nreal) {
                    outf[(size_t)m * Nreal + n] = v;
                }
            }
        }
    }
}

extern "C" void kernel_launch(void* const* d_in, const int* in_sizes, int n_in,
                              void* d_out, int out_size, void* d_ws, size_t ws_size,
                              hipStream_t stream) {
    const float* x   = (const float*)d_in[0];
    const float* h0  = (const float*)d_in[1];
    const float* Wih = (const float*)d_in[2];
    const float* Whh = (const float*)d_in[3];
    const float* bih = (const float*)d_in[4];
    const float* bhh = (const float*)d_in[5];
    const float* w1  = (const float*)d_in[6];
    const float* b1  = (const float*)d_in[7];
    const float* w2  = (const float*)d_in[8];
    const float* b2  = (const float*)d_in[9];
    const float* w3  = (const float*)d_in[10];
    const float* b3  = (const float*)d_in[11];
    const float* w4  = (const float*)d_in[12];
    const float* b4  = (const float*)d_in[13];
    float* out = (float*)d_out;
    char* ws = (char*)d_ws;

    __bf16* w1b = (__bf16*)(ws + 0);          //  1,376,256
    __bf16* w2b = (__bf16*)(ws + 1376256);    //  1,048,576
    __bf16* w3b = (__bf16*)(ws + 2424832);    //    131,072
    __bf16* w4b = (__bf16*)(ws + 2555904);    //    196,608
    __bf16* A0  = (__bf16*)(ws + 2752512);    // 11,010,048  [B, TP]
    __bf16* A1  = (__bf16*)(ws + 13762560);   // 16,777,216  [B, D1]
    __bf16* A2  = (__bf16*)(ws + 30539776);   //  8,388,608  [B, D2]
    __bf16* A3  = (__bf16*)(ws + 38928384);   //  2,097,152  [B, D3]
    __bf16* xwb = (__bf16*)(ws + 13762560);   // 11,010,048  [B, TP] (aliases A1; dead before GEMM1)

    xw_conv_kernel<<<XWBLKS + CVBLKS, 256, 0, stream>>>(
        x, Wih, bih, xwb, w1, w2, w3, w4, w1b, w2b, w3b, w4b);
    scan_kernel<<<128, 64, 0, stream>>>(xwb, h0, Whh, bhh, A0, out + (size_t)B_ * T_);

    gemm_bt<64,128><<<dim3(128, 8), 256, 0, stream>>>(A0, w1b, b1, A1, nullptr, TP,  D1_, D1_, 1);
    gemm_bt<64,64> <<<dim3(128, 8), 256, 0, stream>>>(A1, w2b, b2, A2, nullptr, D1_, D2_, D2_, 1);
    gemm_bt<64,64> <<<dim3(128, 2), 256, 0, stream>>>(A2, w3b, b3, A3, nullptr, D2_, D3_, D3_, 1);
    gemm_bt<64,128><<<dim3(128, 6), 256, 0, stream>>>(A3, w4b, b4, nullptr, out, D3_, NP4, T_, 0);
}